// Round 1
// 85.971 us; speedup vs baseline: 1.0182x; 1.0182x over previous
//
#include <hip/hip_runtime.h>
#include <math.h>

// Problem constants (from reference)
#define B 8
#define T 512
#define D 256
#define S 64
#define P 1024
#define R 12

typedef __attribute__((ext_vector_type(8)))  short bf16x8;   // 8 bf16 = 4 VGPRs
typedef __attribute__((ext_vector_type(16))) float f32x16;   // MFMA 32x32 accum

static __device__ inline short f2bf(float f) {
    union { float f; unsigned u; } v; v.f = f;
    unsigned u = v.u + 0x7fff + ((v.u >> 16) & 1);   // RNE
    return (short)(u >> 16);
}

// -----------------------------------------------------------------------------
// Kernel A (merged): blocks [0,512): ragged span max-pool + per-span linear
// precompute + bf16 span vectors. blocks [512,896): Wb[r][d][e] -> Wt[r][e][d] bf16.
// -----------------------------------------------------------------------------
__global__ __launch_bounds__(256) void k_prep(
    const float* __restrict__ enc, const int* __restrict__ starts,
    const int* __restrict__ lens, const float* __restrict__ Wl,
    const float* __restrict__ Wb,
    short* __restrict__ spb, float* __restrict__ lin, short* __restrict__ Wt)
{
    if (blockIdx.x < B * S) {
        // ---- span max-pool ----
        int bs = blockIdx.x;          // b*S + s
        int b  = bs >> 6;             // S = 64
        int d  = threadIdx.x;
        int st = starts[bs];
        int ln = lens[bs];            // inclusive last offset; ln in [0,11]

        const float* base = enc + ((size_t)(b * T + st)) * D + d;
        float m = base[0];
        // clamped full unroll: independent loads, no serial latency chain
        #pragma unroll
        for (int i = 1; i < 12; ++i) {
            int idx = (i <= ln) ? i : ln;
            m = fmaxf(m, base[(size_t)idx * D]);
        }
        spb[(size_t)bs * D + d] = f2bf(m);

        __shared__ float smem[256];
        smem[d] = m;
        __syncthreads();

        // 24 linear outputs; 4 waves x 6 outputs each, 64-lane shuffle reduce
        int wave = d >> 6, lane = d & 63;
        #pragma unroll
        for (int oo = 0; oo < 6; ++oo) {
            int o = wave * 6 + oo;                 // 0..23
            int r = (o < 12) ? o : (o - 12);
            int rowbase = (o < 12) ? 0 : D;
            float p = 0.f;
            #pragma unroll
            for (int k = 0; k < 4; ++k) {
                int dd = lane + 64 * k;
                p = fmaf(smem[dd], Wl[(size_t)(rowbase + dd) * R + r], p);
            }
            #pragma unroll
            for (int off = 32; off > 0; off >>= 1) p += __shfl_down(p, off, 64);
            if (lane == 0) lin[(size_t)bs * 24 + o] = p;
        }
    } else {
        // ---- Wb transpose + bf16 convert ----
        int bid  = blockIdx.x - B * S;  // 0..383
        int dblk = bid & 31;            // d block (8 rows)
        int r    = bid >> 5;            // 0..11
        int e    = threadIdx.x;         // 0..255

        const float* src = Wb + ((size_t)r * D + dblk * 8) * D + e;
        short v[8];
        #pragma unroll
        for (int j = 0; j < 8; ++j) v[j] = f2bf(src[(size_t)j * D]);

        short* dst = Wt + ((size_t)r * D + e) * D + dblk * 8;
        *(bf16x8*)dst = *(bf16x8*)v;
    }
}

// -----------------------------------------------------------------------------
// Kernel B: fused bilinear + pair gather. Block = (b, r), 4 waves, 1 block/CU
// (96 blocks on 256 CUs) -> VGPRs are free; prefetch aggressively to hide
// post-barrier latency (only ~1 wave/SIMD, no TLP to hide anything).
// Phase 0: prefetch phase-3 gather chain (ph/pt -> lin) and phase-2 B operand
//          (spb rows) into registers.
// Phase 1: U[s,e] = sum_d spb[b,s,d] * Wt[r,e,d]   (64 x 256, K=256, MFMA)
// Phase 2: V[s,t] = sum_e U[s,e] * spb[b,t,e]      (64 x 64,  K=256, MFMA)
//          A from LDS, B from prefetched regs; TWO 8-deep acc chains (halve
//          the serial MFMA dependency latency), merged with 16 v_add_f32.
// Phase 3: out[b,p,r] = sigmoid(V_lds[h*64+t] + linH + linT + bl[r])
// C/D layout (32x32): n = lane&31, m = (reg&3) + 8*(reg>>2) + 4*(lane>>5).
// -----------------------------------------------------------------------------
#define LDSTRIDE 264   // shorts per U row: 256 + 8 pad (row = 528 B, 16B-aligned)
__global__ __launch_bounds__(256, 1) void k_bilinear_gather(
    const short* __restrict__ spb, const short* __restrict__ Wt,
    const float* __restrict__ lin, const int* __restrict__ ph,
    const int* __restrict__ pt, const float* __restrict__ bl,
    float* __restrict__ out)
{
    int b = blockIdx.x;
    int r = blockIdx.y;
    int wave = threadIdx.x >> 6;
    int lane = threadIdx.x & 63;
    int half = lane >> 5;         // k-octet selector
    int mn   = lane & 31;

    __shared__ short ldsU[64 * LDSTRIDE];   // ~33.8 KB
    __shared__ float ldsV[64 * 64];         // 16 KB

    // ---- phase 0a: prefetch pair indices + dependent linear terms + bias ----
    float blr = bl[r];
    int hIdx[4], tIdx[4];
    #pragma unroll
    for (int i = 0; i < 4; ++i) {
        int p = i * 256 + threadIdx.x;
        hIdx[i] = ph[(size_t)b * P + p];
        tIdx[i] = pt[(size_t)b * P + p];
    }
    float linH[4], linT[4];
    #pragma unroll
    for (int i = 0; i < 4; ++i) {
        linH[i] = lin[(size_t)(b * 64 + hIdx[i]) * 24 + r];
        linT[i] = lin[(size_t)(b * 64 + tIdx[i]) * 24 + 12 + r];
    }

    // ---- phase 0b: prefetch phase-2 B operand (spb rows, this wave's t-tile) ----
    int nt2 = (wave & 1) * 32;    // t-half for phase 2
    const short* bp2 = spb + ((size_t)(b * 64 + nt2 + mn)) * D + half * 8;
    bf16x8 b2[16];
    #pragma unroll
    for (int ks = 0; ks < 16; ++ks) b2[ks] = *(const bf16x8*)(bp2 + ks * 16);

    // ---- phase 1: U = spb[b] * Wt[r]^T ----
    {
        int n0 = wave * 64;       // e-quarter
        const short* ap0 = spb + ((size_t)(b * 64 + mn))      * D + half * 8;
        const short* ap1 = ap0 + 32 * D;
        const short* bp0 = Wt + ((size_t)r * D + (n0 + mn))      * D + half * 8;
        const short* bp1 = bp0 + 32 * D;

        f32x16 acc00 = {}, acc01 = {}, acc10 = {}, acc11 = {};
        #pragma unroll
        for (int ks = 0; ks < 16; ++ks) {
            bf16x8 a0 = *(const bf16x8*)(ap0 + ks * 16);
            bf16x8 a1 = *(const bf16x8*)(ap1 + ks * 16);
            bf16x8 b0 = *(const bf16x8*)(bp0 + ks * 16);
            bf16x8 b1 = *(const bf16x8*)(bp1 + ks * 16);
            acc00 = __builtin_amdgcn_mfma_f32_32x32x16_bf16(a0, b0, acc00, 0, 0, 0);
            acc01 = __builtin_amdgcn_mfma_f32_32x32x16_bf16(a0, b1, acc01, 0, 0, 0);
            acc10 = __builtin_amdgcn_mfma_f32_32x32x16_bf16(a1, b0, acc10, 0, 0, 0);
            acc11 = __builtin_amdgcn_mfma_f32_32x32x16_bf16(a1, b1, acc11, 0, 0, 0);
        }

        #pragma unroll
        for (int reg = 0; reg < 16; ++reg) {
            int mrow = (reg & 3) + 8 * (reg >> 2) + 4 * half;
            int e0 = n0 + mn, e1 = n0 + 32 + mn;
            ldsU[(size_t)(mrow)      * LDSTRIDE + e0] = f2bf(acc00[reg]);
            ldsU[(size_t)(mrow)      * LDSTRIDE + e1] = f2bf(acc01[reg]);
            ldsU[(size_t)(mrow + 32) * LDSTRIDE + e0] = f2bf(acc10[reg]);
            ldsU[(size_t)(mrow + 32) * LDSTRIDE + e1] = f2bf(acc11[reg]);
        }
    }
    __syncthreads();

    // ---- phase 2: V = U * spb[b]^T  (to LDS), dual 8-deep acc chains ----
    {
        int mt = (wave >> 1) * 32;    // s-half
        const short* ap = ldsU + (size_t)(mt + mn) * LDSTRIDE + half * 8;

        f32x16 accA = {}, accB = {};
        #pragma unroll
        for (int ks = 0; ks < 8; ++ks) {
            bf16x8 a0 = *(const bf16x8*)(ap + ks * 16);
            bf16x8 a1 = *(const bf16x8*)(ap + (ks + 8) * 16);
            accA = __builtin_amdgcn_mfma_f32_32x32x16_bf16(a0, b2[ks],     accA, 0, 0, 0);
            accB = __builtin_amdgcn_mfma_f32_32x32x16_bf16(a1, b2[ks + 8], accB, 0, 0, 0);
        }

        #pragma unroll
        for (int reg = 0; reg < 16; ++reg) {
            int s = mt + (reg & 3) + 8 * (reg >> 2) + 4 * half;
            int t = nt2 + mn;
            ldsV[s * 64 + t] = accA[reg] + accB[reg];
        }
    }
    __syncthreads();

    // ---- phase 3: pair gather + sigmoid (indices/lin already in regs) ----
    {
        #pragma unroll
        for (int i = 0; i < 4; ++i) {
            int p = i * 256 + threadIdx.x;
            float sc = ldsV[hIdx[i] * 64 + tIdx[i]] + linH[i] + linT[i] + blr;
            out[(size_t)(b * P + p) * R + r] = 1.f / (1.f + __expf(-sc));
        }
    }
}

// -----------------------------------------------------------------------------
extern "C" void kernel_launch(void* const* d_in, const int* in_sizes, int n_in,
                              void* d_out, int out_size, void* d_ws, size_t ws_size,
                              hipStream_t stream) {
    const float* enc    = (const float*)d_in[0];   // [B,T,D]
    const float* Wl     = (const float*)d_in[1];   // [2D,R]
    const float* bl     = (const float*)d_in[2];   // [R]
    const float* Wb     = (const float*)d_in[3];   // [R,D,D]
    const int*   starts = (const int*)d_in[4];     // [B,S]
    const int*   lens   = (const int*)d_in[5];     // [B,S]
    const int*   ph     = (const int*)d_in[6];     // [B,P]
    const int*   pt     = (const int*)d_in[7];     // [B,P]
    float* out = (float*)d_out;                    // [B,P,R]

    // workspace:
    //   lin f32  [512*24]        =  48 KB
    //   spb bf16 [512*256]       = 256 KB
    //   Wt  bf16 [12*256*256]    = 1.5 MB
    float* lin = (float*)d_ws;
    short* spb = (short*)(lin + (size_t)B * S * 24);
    short* Wt  = spb + (size_t)B * S * D;

    k_prep           <<<B * S + 32 * R, 256, 0, stream>>>(enc, starts, lens, Wl, Wb, spb, lin, Wt);
    k_bilinear_gather<<<dim3(B, R),     256, 0, stream>>>(spb, Wt, lin, ph, pt, bl, out);
}